// Round 14
// baseline (518.205 us; speedup 1.0000x reference)
//
#include <hip/hip_runtime.h>
#include <hip/hip_fp16.h>
#include <type_traits>

#define CDIV(a,b) (((a)+(b)-1)/(b))

typedef _Float16 f16x8 __attribute__((ext_vector_type(8)));
typedef float f32x4 __attribute__((ext_vector_type(4)));

// ---------------- W prep (all 3 layers, one dispatch): fp32 row-major -> fp16 fragment-major ----
// element (k,c), k = s*32 + g*8 + i  ->  Wt[((s*4+g)*NOUT + c)*8 + i]
__device__ __forceinline__ void wxform(const float* __restrict__ W,
                                       _Float16* __restrict__ Wt, int i, int NOUT) {
  int k = i / NOUT, c = i % NOUT;
  int s = k >> 5, g = (k >> 3) & 3, e = k & 7;
  Wt[(size_t)((s * 4 + g) * NOUT + c) * 8 + e] = (_Float16)W[i];
}
__global__ __launch_bounds__(256) void wprep_all(const float* __restrict__ W1,
                                                 const float* __restrict__ W2,
                                                 const float* __restrict__ W3,
                                                 _Float16* __restrict__ Wt1,
                                                 _Float16* __restrict__ Wt2,
                                                 _Float16* __restrict__ Wt3) {
  int i = blockIdx.x * blockDim.x + threadIdx.x;
  if (i < 128 * 128) { wxform(W1, Wt1, i, 128); wxform(W2, Wt2, i, 128); }
  if (i < 128 * 64)  { wxform(W3, Wt3, i, 64); }
}

// ---- A-fragment load: fp16 direct or fp32 with convert ----
template<typename AT>
__device__ __forceinline__ f16x8 load_afrag(const AT* __restrict__ xrow) {
  if constexpr (std::is_same<AT, _Float16>::value) {
    return *reinterpret_cast<const f16x8*>(xrow);
  } else {
    float4 v0 = *reinterpret_cast<const float4*>(xrow);
    float4 v1 = *reinterpret_cast<const float4*>(xrow + 4);
    f16x8 r = {(_Float16)v0.x, (_Float16)v0.y, (_Float16)v0.z, (_Float16)v0.w,
               (_Float16)v1.x, (_Float16)v1.y, (_Float16)v1.z, (_Float16)v1.w};
    return r;
  }
}

// ---------------- MFMA GEMM + fused scores ----------------
// Y[n,NOUT](fp16, ROW-major) = X[n,128] @ Wt; also ssrc/sdst[n,h] = <h[n,h,:], a_{s,d}[h,:]>
// one wave per 16-row tile; B-fragments from global (L2-resident); no LDS
template<int NOUT, int HEADS, typename AT>
__global__ __launch_bounds__(256) void gemm_sc(const AT* __restrict__ X,
                                               const _Float16* __restrict__ Wt,
                                               const float* __restrict__ as_,
                                               const float* __restrict__ ad_,
                                               __half* __restrict__ Y,
                                               float* __restrict__ ssrc,
                                               float* __restrict__ sdst, int nrows) {
  constexpr int K = 128;
  constexpr int CT = NOUT / 16;       // col tiles
  constexpr int CH = NOUT / HEADS;    // channels per head
  constexpr int CPH = CH / 16;        // col tiles per head
  const int wave = threadIdx.x >> 6, lane = threadIdx.x & 63;
  const int g = lane >> 4, r16 = lane & 15;
  const int rt = blockIdx.x * 4 + wave;
  if (rt * 16 >= nrows) return;

  const AT* xrow = X + (size_t)(rt * 16 + r16) * K + g * 8;
  f16x8 a[4];
  #pragma unroll
  for (int s = 0; s < 4; ++s) a[s] = load_afrag(xrow + s * 32);

  f32x4 acc[CT];
  #pragma unroll
  for (int ct = 0; ct < CT; ++ct) acc[ct] = (f32x4){0.f, 0.f, 0.f, 0.f};

  #pragma unroll
  for (int ct = 0; ct < CT; ++ct) {
    #pragma unroll
    for (int s = 0; s < 4; ++s) {
      f16x8 b = *reinterpret_cast<const f16x8*>(&Wt[(size_t)((s * 4 + g) * NOUT + ct * 16 + r16) * 8]);
      acc[ct] = __builtin_amdgcn_mfma_f32_16x16x32_f16(a[s], b, acc[ct], 0, 0, 0);
    }
  }
  // C/D: col = lane&15, row = (lane>>4)*4 + reg
  const int row0 = rt * 16 + g * 4;
  #pragma unroll
  for (int ct = 0; ct < CT; ++ct) {
    #pragma unroll
    for (int r = 0; r < 4; ++r) {
      Y[(size_t)(row0 + r) * NOUT + ct * 16 + r16] = __float2half_rn(acc[ct][r]);
    }
  }

  // ---- fused scores: per (row, head) dot with a_s/a_d, reduce over 16-lane group ----
  float pas[4][HEADS], pad_[4][HEADS];
  #pragma unroll
  for (int r = 0; r < 4; ++r)
    #pragma unroll
    for (int h = 0; h < HEADS; ++h) { pas[r][h] = 0.f; pad_[r][h] = 0.f; }
  #pragma unroll
  for (int h = 0; h < HEADS; ++h) {
    #pragma unroll
    for (int q = 0; q < CPH; ++q) {
      float asv = as_[h * CH + q * 16 + r16];
      float adv = ad_[h * CH + q * 16 + r16];
      #pragma unroll
      for (int r = 0; r < 4; ++r) {
        float av = acc[h * CPH + q][r];
        pas[r][h] += av * asv;
        pad_[r][h] += av * adv;
      }
    }
  }
  #pragma unroll
  for (int off = 1; off < 16; off <<= 1) {
    #pragma unroll
    for (int r = 0; r < 4; ++r)
      #pragma unroll
      for (int h = 0; h < HEADS; ++h) {
        pas[r][h] += __shfl_xor(pas[r][h], off);
        pad_[r][h] += __shfl_xor(pad_[r][h], off);
      }
  }
  #pragma unroll
  for (int h = 0; h < HEADS; ++h) {
    if (r16 == h) {
      #pragma unroll
      for (int r = 0; r < 4; ++r) ssrc[(size_t)(row0 + r) * HEADS + h] = pas[r][h];
    }
    if (r16 == 8 + h) {
      #pragma unroll
      for (int r = 0; r < 4; ++r) sdst[(size_t)(row0 + r) * HEADS + h] = pad_[r][h];
    }
  }
}

// ---------------- CSR build: histogram of dst ----------------
__global__ __launch_bounds__(256) void hist_kernel(const int* __restrict__ ei, int E,
                                                   int* __restrict__ deg) {
  int e = blockIdx.x * blockDim.x + threadIdx.x;
  if (e >= E) return;
  atomicAdd(&deg[ei[E + e]], 1);
}

// ---------------- parallel scan, step 1: per-block (1024-chunk) sums ----------------
__global__ __launch_bounds__(256) void scan_blocksums(const int* __restrict__ deg,
                                                      int* __restrict__ bsum, int N) {
  __shared__ int red[256];
  int base = blockIdx.x * 1024 + threadIdx.x * 4;
  int s = 0;
  #pragma unroll
  for (int i = 0; i < 4; ++i) { int idx = base + i; if (idx < N) s += deg[idx]; }
  red[threadIdx.x] = s;
  __syncthreads();
  for (int off = 128; off > 0; off >>= 1) {
    if (threadIdx.x < off) red[threadIdx.x] += red[threadIdx.x + off];
    __syncthreads();
  }
  if (threadIdx.x == 0) bsum[blockIdx.x] = red[0];
}

// ---------------- parallel scan, step 2: exclusive scan of block sums (nb <= 1024) ----------------
__global__ __launch_bounds__(1024) void scan_bsum(int* __restrict__ bsum, int nb) {
  __shared__ int sh[1024];
  int t = threadIdx.x;
  int v = (t < nb) ? bsum[t] : 0;
  sh[t] = v;
  __syncthreads();
  for (int off = 1; off < 1024; off <<= 1) {
    int tmp = (t >= off) ? sh[t - off] : 0;
    __syncthreads();
    sh[t] += tmp;
    __syncthreads();
  }
  if (t < nb) bsum[t] = sh[t] - v;   // exclusive
}

// ---------------- parallel scan, step 3: per-block rescan + offset, emit rowptr/cursor ----------------
__global__ __launch_bounds__(256) void scan_final(const int* __restrict__ deg,
                                                  const int* __restrict__ bsum,
                                                  int* __restrict__ rowptr,
                                                  int* __restrict__ cursor, int N) {
  __shared__ int sh[256];
  const int t = threadIdx.x;
  const int base = blockIdx.x * 1024 + t * 4;
  int d[4] = {0, 0, 0, 0};
  #pragma unroll
  for (int i = 0; i < 4; ++i) if (base + i < N) d[i] = deg[base + i];
  int s = d[0] + d[1] + d[2] + d[3];
  sh[t] = s;
  __syncthreads();
  for (int off = 1; off < 256; off <<= 1) {
    int tmp = (t >= off) ? sh[t - off] : 0;
    __syncthreads();
    sh[t] += tmp;
    __syncthreads();
  }
  int run = bsum[blockIdx.x] + sh[t] - s;   // exclusive prefix for this thread
  #pragma unroll
  for (int i = 0; i < 4; ++i) {
    if (base + i < N) { rowptr[base + i] = run; cursor[base + i] = run; run += d[i]; }
  }
  if (blockIdx.x == gridDim.x - 1 && t == 255) rowptr[N] = run;   // total (= E)
}

// ---------------- CSR scatter, range-split over dst to keep col region L2-resident ----------------
__global__ __launch_bounds__(256) void scatter_pass(const int* __restrict__ ei, int E, int N,
                                                    int pw,
                                                    int* __restrict__ cursor,
                                                    int* __restrict__ col) {
  int e = blockIdx.x * blockDim.x + threadIdx.x;
  if (e >= E) return;
  int lo = blockIdx.y * pw;
  int hi = lo + pw;
  int d = ei[E + e];
  if (d < lo || d >= hi) return;
  int pos = atomicAdd(&cursor[d], 1);
  col[pos] = ei[e];
}

// --------- FUSED softmax + aggregation: one wave per node, one edge pass (R7/R9 structure) ---------
// stabilizer K = self logit (leaky_relu monotone + softmax shift-invariance => exact)
// phase B: 16 fully-unrolled 4B/lane gathers with LDS-tile (p,src) indirection — proven optimum.
// THIS ROUND'S ONLY CHANGE: cvt+FMA pair -> v_fma_mix_f32 (f16 src fused into fp32 FMA, exact).
template<int HEADS, int CH, bool BN, bool OUTH>
__global__ __launch_bounds__(256) void gat_fused(
    const int* __restrict__ rowptr, const int* __restrict__ col,
    const __half* __restrict__ Hf,
    const float* __restrict__ ssrc, const float* __restrict__ sdst,
    const float* __restrict__ bias, const float* __restrict__ g,
    const float* __restrict__ be, const float* __restrict__ rm,
    const float* __restrict__ rv,
    void* __restrict__ outp, int N) {
  constexpr int NOUT = HEADS * CH;
  constexpr int VEC = NOUT / 64;       // 2 (128ch) or 1 (64ch)
  constexpr int SLOTS = 64 / HEADS;    // edges per tile
  __shared__ float ptile[4][SLOTS][HEADS];
  __shared__ int   stile[4][SLOTS];
  const int wv = threadIdx.x >> 6, lane = threadIdx.x & 63;
  const int n = blockIdx.x * 4 + wv;
  if (n >= N) return;
  const int eslot = lane / HEADS, head = lane & (HEADS - 1);
  const float sd = sdst[n * HEADS + head];
  float lgs = ssrc[n * HEADS + head] + sd;       // self logit = stabilizer K
  lgs = lgs > 0.f ? lgs : 0.2f * lgs;

  // phase-B channel mapping
  const int c0 = lane * VEC;
  const int hb = c0 / CH;

  // self contribution: p_self = exp(lgs - K) = 1
  float a0, a1 = 0.f;
  if (VEC == 2) {
    float2 hf = __half22float2(*reinterpret_cast<const __half2*>(&Hf[(size_t)n * NOUT + c0]));
    a0 = hf.x; a1 = hf.y;
  } else {
    a0 = __half2float(Hf[(size_t)n * NOUT + c0]);
  }

  float s = 0.f;                                  // sum of p over real edges
  const int beg = rowptr[n], end = rowptr[n + 1];
  for (int base = beg; base < end; base += SLOTS) {
    // phase A: lanes over (edge-slot, head) -> p into LDS
    int e = base + eslot;
    float p = 0.f; int src = 0;
    if (e < end) {
      src = col[e];
      float lg = ssrc[src * HEADS + head] + sd;
      lg = lg > 0.f ? lg : 0.2f * lg;
      p = __expf(lg - lgs);
    }
    ptile[wv][eslot][head] = p;                  // p=0 pads tail slots
    if (head == 0) stile[wv][eslot] = src;
    s += p;
    asm volatile("s_waitcnt lgkmcnt(0)" ::: "memory");   // wave-local LDS visibility

    // phase B: lanes over channels, gather-FMA (v_fma_mix: f16->f32 convert fused into FMA)
    int cnt = min(SLOTS, end - base);
    if (cnt == SLOTS) {
      #pragma unroll 16
      for (int j = 0; j < SLOTS; ++j) {
        int sj = stile[wv][j];
        float pj = ptile[wv][j][hb];
        if (VEC == 2) {
          unsigned hraw = *reinterpret_cast<const unsigned*>(&Hf[(size_t)sj * NOUT + c0]);
          asm("v_fma_mix_f32 %0, %1, %2, %0 op_sel_hi:[1,0,0]"
              : "+v"(a0) : "v"(hraw), "v"(pj));
          asm("v_fma_mix_f32 %0, %1, %2, %0 op_sel:[1,0,0] op_sel_hi:[1,0,0]"
              : "+v"(a1) : "v"(hraw), "v"(pj));
        } else {
          unsigned hraw = *reinterpret_cast<const unsigned short*>(&Hf[(size_t)sj * NOUT + c0]);
          asm("v_fma_mix_f32 %0, %1, %2, %0 op_sel_hi:[1,0,0]"
              : "+v"(a0) : "v"(hraw), "v"(pj));
        }
      }
    } else {
      for (int j = 0; j < cnt; ++j) {
        int sj = stile[wv][j];
        float pj = ptile[wv][j][hb];
        if (VEC == 2) {
          unsigned hraw = *reinterpret_cast<const unsigned*>(&Hf[(size_t)sj * NOUT + c0]);
          asm("v_fma_mix_f32 %0, %1, %2, %0 op_sel_hi:[1,0,0]"
              : "+v"(a0) : "v"(hraw), "v"(pj));
          asm("v_fma_mix_f32 %0, %1, %2, %0 op_sel:[1,0,0] op_sel_hi:[1,0,0]"
              : "+v"(a1) : "v"(hraw), "v"(pj));
        } else {
          unsigned hraw = *reinterpret_cast<const unsigned short*>(&Hf[(size_t)sj * NOUT + c0]);
          asm("v_fma_mix_f32 %0, %1, %2, %0 op_sel_hi:[1,0,0]"
              : "+v"(a0) : "v"(hraw), "v"(pj));
        }
      }
    }
  }

  // denominator: reduce p-sums across edge-slots (per head), add self
  #pragma unroll
  for (int off = HEADS; off < 64; off <<= 1) s += __shfl_xor(s, off);
  float inv = 1.f / (s + 1.f);                    // lane's value valid for head = lane&(H-1)
  float invb = __shfl(inv, hb);                   // lane hb holds head hb

  float o0 = a0 * invb + bias[c0];
  if (BN) {
    o0 = (o0 - rm[c0]) * rsqrtf(rv[c0] + 1e-5f) * g[c0] + be[c0];
    o0 = o0 > 0.f ? o0 : expm1f(o0);
  }
  if (VEC == 2) {
    float o1 = a1 * invb + bias[c0 + 1];
    if (BN) {
      o1 = (o1 - rm[c0 + 1]) * rsqrtf(rv[c0 + 1] + 1e-5f) * g[c0 + 1] + be[c0 + 1];
      o1 = o1 > 0.f ? o1 : expm1f(o1);
    }
    if (OUTH) {
      __half2 o = __floats2half2_rn(o0, o1);
      *reinterpret_cast<__half2*>(&((__half*)outp)[(size_t)n * NOUT + c0]) = o;
    } else {
      float2 o = make_float2(o0, o1);
      *reinterpret_cast<float2*>(&((float*)outp)[(size_t)n * NOUT + c0]) = o;
    }
  } else {
    if (OUTH) ((__half*)outp)[(size_t)n * NOUT + c0] = __float2half_rn(o0);
    else      ((float*)outp)[(size_t)n * NOUT + c0] = o0;
  }
}

extern "C" void kernel_launch(void* const* d_in, const int* in_sizes, int n_in,
                              void* d_out, int out_size, void* d_ws, size_t ws_size,
                              hipStream_t stream) {
  const float* x   = (const float*)d_in[0];
  const int*   ei  = (const int*)d_in[1];
  const float* W1  = (const float*)d_in[2];
  const float* as1 = (const float*)d_in[3];
  const float* ad1 = (const float*)d_in[4];
  const float* b1  = (const float*)d_in[5];
  const float* g1  = (const float*)d_in[6];
  const float* be1 = (const float*)d_in[7];
  const float* rm1 = (const float*)d_in[8];
  const float* rv1 = (const float*)d_in[9];
  const float* W2  = (const float*)d_in[10];
  const float* as2 = (const float*)d_in[11];
  const float* ad2 = (const float*)d_in[12];
  const float* b2  = (const float*)d_in[13];
  const float* g2  = (const float*)d_in[14];
  const float* be2 = (const float*)d_in[15];
  const float* rm2 = (const float*)d_in[16];
  const float* rv2 = (const float*)d_in[17];
  const float* W3  = (const float*)d_in[18];
  const float* as3 = (const float*)d_in[19];
  const float* ad3 = (const float*)d_in[20];
  const float* b3  = (const float*)d_in[21];

  const int N = in_sizes[0] / 128;
  const int E = in_sizes[1] / 2;
  float* out = (float*)d_out;

  // workspace layout (bytes)
  char* p = (char*)d_ws;
  __half* Ah  = (__half*)p;  p += (size_t)N * 128 * 2;   // h buffer (GEMM out)
  __half* Bh  = (__half*)p;  p += (size_t)N * 128 * 2;   // layer in/out (fp16)
  float* ssrc = (float*)p;   p += (size_t)N * 4 * 4;
  float* sdst = (float*)p;   p += (size_t)N * 4 * 4;
  int* deg    = (int*)p;     p += (size_t)N * 4;
  int* rowptr = (int*)p;     p += (size_t)(N + 1) * 4;
  int* cursor = (int*)p;     p += (size_t)N * 4;
  int* col    = (int*)p;     p += (size_t)E * 4;
  int* bsum   = (int*)p;     p += 4096;
  _Float16* Wt1 = (_Float16*)p; p += (size_t)128 * 128 * 2;
  _Float16* Wt2 = (_Float16*)p; p += (size_t)128 * 128 * 2;
  _Float16* Wt3 = (_Float16*)p;

  const int fusedB = CDIV(N, 4);                 // one wave per node, 4 waves/block
  const int nb = CDIV(N, 1024);                  // scan blocks
  const int gemmB = CDIV(N, 64);                 // 4 row-tiles (16 rows) per block
  constexpr int NPASS = 8;
  const int pw = CDIV(N, NPASS);

  // ---------------- CSR build (by dst), reused by all 3 layers ----------------
  hipMemsetAsync(deg, 0, (size_t)N * sizeof(int), stream);
  hist_kernel<<<CDIV(E, 256), 256, 0, stream>>>(ei, E, deg);
  scan_blocksums<<<nb, 256, 0, stream>>>(deg, bsum, N);
  scan_bsum<<<1, 1024, 0, stream>>>(bsum, nb);
  scan_final<<<nb, 256, 0, stream>>>(deg, bsum, rowptr, cursor, N);
  scatter_pass<<<dim3(CDIV(E, 256), NPASS), 256, 0, stream>>>(ei, E, N, pw, cursor, col);

  // W -> fragment-major fp16, all layers in one dispatch
  wprep_all<<<CDIV(128 * 128, 256), 256, 0, stream>>>(W1, W2, W3, Wt1, Wt2, Wt3);

  // ---------------- layer 1: GAT(128 -> 4x32) + BN + ELU  (reads fp32 x directly) -------
  gemm_sc<128, 4, float><<<gemmB, 256, 0, stream>>>(x, Wt1, as1, ad1, Ah, ssrc, sdst, N);
  gat_fused<4, 32, true, true><<<fusedB, 256, 0, stream>>>(rowptr, col, Ah, ssrc, sdst,
                                                           b1, g1, be1, rm1, rv1, Bh, N);

  // ---------------- layer 2: GAT(128 -> 4x32) + BN + ELU ----------------
  gemm_sc<128, 4, _Float16><<<gemmB, 256, 0, stream>>>((const _Float16*)Bh, Wt2, as2, ad2,
                                                       Ah, ssrc, sdst, N);
  gat_fused<4, 32, true, true><<<fusedB, 256, 0, stream>>>(rowptr, col, Ah, ssrc, sdst,
                                                           b2, g2, be2, rm2, rv2, Bh, N);

  // ---------------- layer 3: GAT(128 -> 64, heads=1, no BN), fp32 out ----------------
  gemm_sc<64, 1, _Float16><<<gemmB, 256, 0, stream>>>((const _Float16*)Bh, Wt3, as3, ad3,
                                                      Ah, ssrc, sdst, N);
  gat_fused<1, 64, false, false><<<fusedB, 256, 0, stream>>>(rowptr, col, Ah, ssrc, sdst,
                                                             b3, b3, b3, b3, b3, out, N);
}

// Round 15
// 448.394 us; speedup vs baseline: 1.1557x; 1.1557x over previous
//
#include <hip/hip_runtime.h>
#include <hip/hip_fp16.h>
#include <type_traits>

#define CDIV(a,b) (((a)+(b)-1)/(b))

typedef _Float16 f16x8 __attribute__((ext_vector_type(8)));
typedef float f32x4 __attribute__((ext_vector_type(4)));

// ---------------- W prep (all 3 layers, one dispatch): fp32 row-major -> fp16 fragment-major ----
// element (k,c), k = s*32 + g*8 + i  ->  Wt[((s*4+g)*NOUT + c)*8 + i]
__device__ __forceinline__ void wxform(const float* __restrict__ W,
                                       _Float16* __restrict__ Wt, int i, int NOUT) {
  int k = i / NOUT, c = i % NOUT;
  int s = k >> 5, g = (k >> 3) & 3, e = k & 7;
  Wt[(size_t)((s * 4 + g) * NOUT + c) * 8 + e] = (_Float16)W[i];
}
__global__ __launch_bounds__(256) void wprep_all(const float* __restrict__ W1,
                                                 const float* __restrict__ W2,
                                                 const float* __restrict__ W3,
                                                 _Float16* __restrict__ Wt1,
                                                 _Float16* __restrict__ Wt2,
                                                 _Float16* __restrict__ Wt3) {
  int i = blockIdx.x * blockDim.x + threadIdx.x;
  if (i < 128 * 128) { wxform(W1, Wt1, i, 128); wxform(W2, Wt2, i, 128); }
  if (i < 128 * 64)  { wxform(W3, Wt3, i, 64); }
}

// ---- A-fragment load: fp16 direct or fp32 with convert ----
template<typename AT>
__device__ __forceinline__ f16x8 load_afrag(const AT* __restrict__ xrow) {
  if constexpr (std::is_same<AT, _Float16>::value) {
    return *reinterpret_cast<const f16x8*>(xrow);
  } else {
    float4 v0 = *reinterpret_cast<const float4*>(xrow);
    float4 v1 = *reinterpret_cast<const float4*>(xrow + 4);
    f16x8 r = {(_Float16)v0.x, (_Float16)v0.y, (_Float16)v0.z, (_Float16)v0.w,
               (_Float16)v1.x, (_Float16)v1.y, (_Float16)v1.z, (_Float16)v1.w};
    return r;
  }
}

// ---------------- MFMA GEMM + fused scores ----------------
// Y[n,NOUT](fp16, ROW-major) = X[n,128] @ Wt; also ssrc/sdst[n,h] = <h[n,h,:], a_{s,d}[h,:]>
// one wave per 16-row tile; B-fragments from global (L2-resident); no LDS
template<int NOUT, int HEADS, typename AT>
__global__ __launch_bounds__(256) void gemm_sc(const AT* __restrict__ X,
                                               const _Float16* __restrict__ Wt,
                                               const float* __restrict__ as_,
                                               const float* __restrict__ ad_,
                                               __half* __restrict__ Y,
                                               float* __restrict__ ssrc,
                                               float* __restrict__ sdst, int nrows) {
  constexpr int K = 128;
  constexpr int CT = NOUT / 16;       // col tiles
  constexpr int CH = NOUT / HEADS;    // channels per head
  constexpr int CPH = CH / 16;        // col tiles per head
  const int wave = threadIdx.x >> 6, lane = threadIdx.x & 63;
  const int g = lane >> 4, r16 = lane & 15;
  const int rt = blockIdx.x * 4 + wave;
  if (rt * 16 >= nrows) return;

  const AT* xrow = X + (size_t)(rt * 16 + r16) * K + g * 8;
  f16x8 a[4];
  #pragma unroll
  for (int s = 0; s < 4; ++s) a[s] = load_afrag(xrow + s * 32);

  f32x4 acc[CT];
  #pragma unroll
  for (int ct = 0; ct < CT; ++ct) acc[ct] = (f32x4){0.f, 0.f, 0.f, 0.f};

  #pragma unroll
  for (int ct = 0; ct < CT; ++ct) {
    #pragma unroll
    for (int s = 0; s < 4; ++s) {
      f16x8 b = *reinterpret_cast<const f16x8*>(&Wt[(size_t)((s * 4 + g) * NOUT + ct * 16 + r16) * 8]);
      acc[ct] = __builtin_amdgcn_mfma_f32_16x16x32_f16(a[s], b, acc[ct], 0, 0, 0);
    }
  }
  // C/D: col = lane&15, row = (lane>>4)*4 + reg
  const int row0 = rt * 16 + g * 4;
  #pragma unroll
  for (int ct = 0; ct < CT; ++ct) {
    #pragma unroll
    for (int r = 0; r < 4; ++r) {
      Y[(size_t)(row0 + r) * NOUT + ct * 16 + r16] = __float2half_rn(acc[ct][r]);
    }
  }

  // ---- fused scores: per (row, head) dot with a_s/a_d, reduce over 16-lane group ----
  float pas[4][HEADS], pad_[4][HEADS];
  #pragma unroll
  for (int r = 0; r < 4; ++r)
    #pragma unroll
    for (int h = 0; h < HEADS; ++h) { pas[r][h] = 0.f; pad_[r][h] = 0.f; }
  #pragma unroll
  for (int h = 0; h < HEADS; ++h) {
    #pragma unroll
    for (int q = 0; q < CPH; ++q) {
      float asv = as_[h * CH + q * 16 + r16];
      float adv = ad_[h * CH + q * 16 + r16];
      #pragma unroll
      for (int r = 0; r < 4; ++r) {
        float av = acc[h * CPH + q][r];
        pas[r][h] += av * asv;
        pad_[r][h] += av * adv;
      }
    }
  }
  #pragma unroll
  for (int off = 1; off < 16; off <<= 1) {
    #pragma unroll
    for (int r = 0; r < 4; ++r)
      #pragma unroll
      for (int h = 0; h < HEADS; ++h) {
        pas[r][h] += __shfl_xor(pas[r][h], off);
        pad_[r][h] += __shfl_xor(pad_[r][h], off);
      }
  }
  #pragma unroll
  for (int h = 0; h < HEADS; ++h) {
    if (r16 == h) {
      #pragma unroll
      for (int r = 0; r < 4; ++r) ssrc[(size_t)(row0 + r) * HEADS + h] = pas[r][h];
    }
    if (r16 == 8 + h) {
      #pragma unroll
      for (int r = 0; r < 4; ++r) sdst[(size_t)(row0 + r) * HEADS + h] = pad_[r][h];
    }
  }
}

// ---------------- CSR build: histogram of dst ----------------
__global__ __launch_bounds__(256) void hist_kernel(const int* __restrict__ ei, int E,
                                                   int* __restrict__ deg) {
  int e = blockIdx.x * blockDim.x + threadIdx.x;
  if (e >= E) return;
  atomicAdd(&deg[ei[E + e]], 1);
}

// ---------------- parallel scan, step 1: per-block (1024-chunk) sums ----------------
__global__ __launch_bounds__(256) void scan_blocksums(const int* __restrict__ deg,
                                                      int* __restrict__ bsum, int N) {
  __shared__ int red[256];
  int base = blockIdx.x * 1024 + threadIdx.x * 4;
  int s = 0;
  #pragma unroll
  for (int i = 0; i < 4; ++i) { int idx = base + i; if (idx < N) s += deg[idx]; }
  red[threadIdx.x] = s;
  __syncthreads();
  for (int off = 128; off > 0; off >>= 1) {
    if (threadIdx.x < off) red[threadIdx.x] += red[threadIdx.x + off];
    __syncthreads();
  }
  if (threadIdx.x == 0) bsum[blockIdx.x] = red[0];
}

// ---------------- parallel scan, step 2: exclusive scan of block sums (nb <= 1024) ----------------
__global__ __launch_bounds__(1024) void scan_bsum(int* __restrict__ bsum, int nb) {
  __shared__ int sh[1024];
  int t = threadIdx.x;
  int v = (t < nb) ? bsum[t] : 0;
  sh[t] = v;
  __syncthreads();
  for (int off = 1; off < 1024; off <<= 1) {
    int tmp = (t >= off) ? sh[t - off] : 0;
    __syncthreads();
    sh[t] += tmp;
    __syncthreads();
  }
  if (t < nb) bsum[t] = sh[t] - v;   // exclusive
}

// ---------------- parallel scan, step 3: per-block rescan + offset, emit rowptr/cursor ----------------
__global__ __launch_bounds__(256) void scan_final(const int* __restrict__ deg,
                                                  const int* __restrict__ bsum,
                                                  int* __restrict__ rowptr,
                                                  int* __restrict__ cursor, int N) {
  __shared__ int sh[256];
  const int t = threadIdx.x;
  const int base = blockIdx.x * 1024 + t * 4;
  int d[4] = {0, 0, 0, 0};
  #pragma unroll
  for (int i = 0; i < 4; ++i) if (base + i < N) d[i] = deg[base + i];
  int s = d[0] + d[1] + d[2] + d[3];
  sh[t] = s;
  __syncthreads();
  for (int off = 1; off < 256; off <<= 1) {
    int tmp = (t >= off) ? sh[t - off] : 0;
    __syncthreads();
    sh[t] += tmp;
    __syncthreads();
  }
  int run = bsum[blockIdx.x] + sh[t] - s;   // exclusive prefix for this thread
  #pragma unroll
  for (int i = 0; i < 4; ++i) {
    if (base + i < N) { rowptr[base + i] = run; cursor[base + i] = run; run += d[i]; }
  }
  if (blockIdx.x == gridDim.x - 1 && t == 255) rowptr[N] = run;   // total (= E)
}

// ---------------- CSR scatter, range-split over dst to keep col region L2-resident ----------------
__global__ __launch_bounds__(256) void scatter_pass(const int* __restrict__ ei, int E, int N,
                                                    int pw,
                                                    int* __restrict__ cursor,
                                                    int* __restrict__ col) {
  int e = blockIdx.x * blockDim.x + threadIdx.x;
  if (e >= E) return;
  int lo = blockIdx.y * pw;
  int hi = lo + pw;
  int d = ei[E + e];
  if (d < lo || d >= hi) return;
  int pos = atomicAdd(&cursor[d], 1);
  col[pos] = ei[e];
}

// --------- FUSED softmax + aggregation: one wave per node, one edge pass (R7/R9 structure) ---------
// stabilizer K = self logit (leaky_relu monotone + softmax shift-invariance => exact)
// phase B: 16 fully-unrolled 4B/lane gathers with LDS-tile (p,src) indirection — proven optimum.
// DO NOT restructure phase B: R8 (shuffle), R10 (wide-load), R11/12 (XCD-slice), R14 (fma_mix asm)
// all regressed. The kernel is load-concurrency-bound; this structure maximizes loads in flight.
template<int HEADS, int CH, bool BN, bool OUTH>
__global__ __launch_bounds__(256) void gat_fused(
    const int* __restrict__ rowptr, const int* __restrict__ col,
    const __half* __restrict__ Hf,
    const float* __restrict__ ssrc, const float* __restrict__ sdst,
    const float* __restrict__ bias, const float* __restrict__ g,
    const float* __restrict__ be, const float* __restrict__ rm,
    const float* __restrict__ rv,
    void* __restrict__ outp, int N) {
  constexpr int NOUT = HEADS * CH;
  constexpr int VEC = NOUT / 64;       // 2 (128ch) or 1 (64ch)
  constexpr int SLOTS = 64 / HEADS;    // edges per tile
  __shared__ float ptile[4][SLOTS][HEADS];
  __shared__ int   stile[4][SLOTS];
  const int wv = threadIdx.x >> 6, lane = threadIdx.x & 63;
  const int n = blockIdx.x * 4 + wv;
  if (n >= N) return;
  const int eslot = lane / HEADS, head = lane & (HEADS - 1);
  const float sd = sdst[n * HEADS + head];
  float lgs = ssrc[n * HEADS + head] + sd;       // self logit = stabilizer K
  lgs = lgs > 0.f ? lgs : 0.2f * lgs;

  // phase-B channel mapping
  const int c0 = lane * VEC;
  const int hb = c0 / CH;

  // self contribution: p_self = exp(lgs - K) = 1
  float a0, a1 = 0.f;
  if (VEC == 2) {
    float2 hf = __half22float2(*reinterpret_cast<const __half2*>(&Hf[(size_t)n * NOUT + c0]));
    a0 = hf.x; a1 = hf.y;
  } else {
    a0 = __half2float(Hf[(size_t)n * NOUT + c0]);
  }

  float s = 0.f;                                  // sum of p over real edges
  const int beg = rowptr[n], end = rowptr[n + 1];
  for (int base = beg; base < end; base += SLOTS) {
    // phase A: lanes over (edge-slot, head) -> p into LDS
    int e = base + eslot;
    float p = 0.f; int src = 0;
    if (e < end) {
      src = col[e];
      float lg = ssrc[src * HEADS + head] + sd;
      lg = lg > 0.f ? lg : 0.2f * lg;
      p = __expf(lg - lgs);
    }
    ptile[wv][eslot][head] = p;                  // p=0 pads tail slots
    if (head == 0) stile[wv][eslot] = src;
    s += p;
    asm volatile("s_waitcnt lgkmcnt(0)" ::: "memory");   // wave-local LDS visibility

    // phase B: lanes over channels, gather-FMA
    int cnt = min(SLOTS, end - base);
    if (cnt == SLOTS) {
      #pragma unroll 16
      for (int j = 0; j < SLOTS; ++j) {
        int sj = stile[wv][j];
        float pj = ptile[wv][j][hb];
        if (VEC == 2) {
          float2 hf = __half22float2(*reinterpret_cast<const __half2*>(&Hf[(size_t)sj * NOUT + c0]));
          a0 += pj * hf.x; a1 += pj * hf.y;
        } else {
          a0 += pj * __half2float(Hf[(size_t)sj * NOUT + c0]);
        }
      }
    } else {
      for (int j = 0; j < cnt; ++j) {
        int sj = stile[wv][j];
        float pj = ptile[wv][j][hb];
        if (VEC == 2) {
          float2 hf = __half22float2(*reinterpret_cast<const __half2*>(&Hf[(size_t)sj * NOUT + c0]));
          a0 += pj * hf.x; a1 += pj * hf.y;
        } else {
          a0 += pj * __half2float(Hf[(size_t)sj * NOUT + c0]);
        }
      }
    }
  }

  // denominator: reduce p-sums across edge-slots (per head), add self
  #pragma unroll
  for (int off = HEADS; off < 64; off <<= 1) s += __shfl_xor(s, off);
  float inv = 1.f / (s + 1.f);                    // lane's value valid for head = lane&(H-1)
  float invb = __shfl(inv, hb);                   // lane hb holds head hb

  float o0 = a0 * invb + bias[c0];
  if (BN) {
    o0 = (o0 - rm[c0]) * rsqrtf(rv[c0] + 1e-5f) * g[c0] + be[c0];
    o0 = o0 > 0.f ? o0 : expm1f(o0);
  }
  if (VEC == 2) {
    float o1 = a1 * invb + bias[c0 + 1];
    if (BN) {
      o1 = (o1 - rm[c0 + 1]) * rsqrtf(rv[c0 + 1] + 1e-5f) * g[c0 + 1] + be[c0 + 1];
      o1 = o1 > 0.f ? o1 : expm1f(o1);
    }
    if (OUTH) {
      __half2 o = __floats2half2_rn(o0, o1);
      *reinterpret_cast<__half2*>(&((__half*)outp)[(size_t)n * NOUT + c0]) = o;
    } else {
      float2 o = make_float2(o0, o1);
      *reinterpret_cast<float2*>(&((float*)outp)[(size_t)n * NOUT + c0]) = o;
    }
  } else {
    if (OUTH) ((__half*)outp)[(size_t)n * NOUT + c0] = __float2half_rn(o0);
    else      ((float*)outp)[(size_t)n * NOUT + c0] = o0;
  }
}

extern "C" void kernel_launch(void* const* d_in, const int* in_sizes, int n_in,
                              void* d_out, int out_size, void* d_ws, size_t ws_size,
                              hipStream_t stream) {
  const float* x   = (const float*)d_in[0];
  const int*   ei  = (const int*)d_in[1];
  const float* W1  = (const float*)d_in[2];
  const float* as1 = (const float*)d_in[3];
  const float* ad1 = (const float*)d_in[4];
  const float* b1  = (const float*)d_in[5];
  const float* g1  = (const float*)d_in[6];
  const float* be1 = (const float*)d_in[7];
  const float* rm1 = (const float*)d_in[8];
  const float* rv1 = (const float*)d_in[9];
  const float* W2  = (const float*)d_in[10];
  const float* as2 = (const float*)d_in[11];
  const float* ad2 = (const float*)d_in[12];
  const float* b2  = (const float*)d_in[13];
  const float* g2  = (const float*)d_in[14];
  const float* be2 = (const float*)d_in[15];
  const float* rm2 = (const float*)d_in[16];
  const float* rv2 = (const float*)d_in[17];
  const float* W3  = (const float*)d_in[18];
  const float* as3 = (const float*)d_in[19];
  const float* ad3 = (const float*)d_in[20];
  const float* b3  = (const float*)d_in[21];

  const int N = in_sizes[0] / 128;
  const int E = in_sizes[1] / 2;
  float* out = (float*)d_out;

  // workspace layout (bytes)
  char* p = (char*)d_ws;
  __half* Ah  = (__half*)p;  p += (size_t)N * 128 * 2;   // h buffer (GEMM out)
  __half* Bh  = (__half*)p;  p += (size_t)N * 128 * 2;   // layer in/out (fp16)
  float* ssrc = (float*)p;   p += (size_t)N * 4 * 4;
  float* sdst = (float*)p;   p += (size_t)N * 4 * 4;
  int* deg    = (int*)p;     p += (size_t)N * 4;
  int* rowptr = (int*)p;     p += (size_t)(N + 1) * 4;
  int* cursor = (int*)p;     p += (size_t)N * 4;
  int* col    = (int*)p;     p += (size_t)E * 4;
  int* bsum   = (int*)p;     p += 4096;
  _Float16* Wt1 = (_Float16*)p; p += (size_t)128 * 128 * 2;
  _Float16* Wt2 = (_Float16*)p; p += (size_t)128 * 128 * 2;
  _Float16* Wt3 = (_Float16*)p;

  const int fusedB = CDIV(N, 4);                 // one wave per node, 4 waves/block
  const int nb = CDIV(N, 1024);                  // scan blocks
  const int gemmB = CDIV(N, 64);                 // 4 row-tiles (16 rows) per block
  constexpr int NPASS = 8;
  const int pw = CDIV(N, NPASS);

  // ---------------- CSR build (by dst), reused by all 3 layers ----------------
  hipMemsetAsync(deg, 0, (size_t)N * sizeof(int), stream);
  hist_kernel<<<CDIV(E, 256), 256, 0, stream>>>(ei, E, deg);
  scan_blocksums<<<nb, 256, 0, stream>>>(deg, bsum, N);
  scan_bsum<<<1, 1024, 0, stream>>>(bsum, nb);
  scan_final<<<nb, 256, 0, stream>>>(deg, bsum, rowptr, cursor, N);
  scatter_pass<<<dim3(CDIV(E, 256), NPASS), 256, 0, stream>>>(ei, E, N, pw, cursor, col);

  // W -> fragment-major fp16, all layers in one dispatch
  wprep_all<<<CDIV(128 * 128, 256), 256, 0, stream>>>(W1, W2, W3, Wt1, Wt2, Wt3);

  // ---------------- layer 1: GAT(128 -> 4x32) + BN + ELU  (reads fp32 x directly) -------
  gemm_sc<128, 4, float><<<gemmB, 256, 0, stream>>>(x, Wt1, as1, ad1, Ah, ssrc, sdst, N);
  gat_fused<4, 32, true, true><<<fusedB, 256, 0, stream>>>(rowptr, col, Ah, ssrc, sdst,
                                                           b1, g1, be1, rm1, rv1, Bh, N);

  // ---------------- layer 2: GAT(128 -> 4x32) + BN + ELU ----------------
  gemm_sc<128, 4, _Float16><<<gemmB, 256, 0, stream>>>((const _Float16*)Bh, Wt2, as2, ad2,
                                                       Ah, ssrc, sdst, N);
  gat_fused<4, 32, true, true><<<fusedB, 256, 0, stream>>>(rowptr, col, Ah, ssrc, sdst,
                                                           b2, g2, be2, rm2, rv2, Bh, N);

  // ---------------- layer 3: GAT(128 -> 64, heads=1, no BN), fp32 out ----------------
  gemm_sc<64, 1, _Float16><<<gemmB, 256, 0, stream>>>((const _Float16*)Bh, Wt3, as3, ad3,
                                                      Ah, ssrc, sdst, N);
  gat_fused<1, 64, false, false><<<fusedB, 256, 0, stream>>>(rowptr, col, Ah, ssrc, sdst,
                                                             b3, b3, b3, b3, b3, out, N);
}